// Round 3
// baseline (1011.292 us; speedup 1.0000x reference)
//
#include <hip/hip_runtime.h>
#include <hip/hip_bf16.h>

#define N_NODES 100000
#define N_EDGES 1600000
#define D_FEAT 256
#define HIDDEN 256
#define N_CLASSES 64

#define NBKT 391                // buckets of 256 nodes: 99999>>8 = 390
#define TILE 4096               // edges per bin_scatter block
#define CAP  8192               // bucket_fill LDS staging (mean 4093, sigma 64)
#define RB_TOT 6256             // 16-row blocks covering 782*128 = 100096 rows
#define NPAD 100096             // padded rows per feature-chunk (chunk-major layouts)

typedef __attribute__((ext_vector_type(8))) short bf16x8;
typedef __attribute__((ext_vector_type(4))) float f32x4;
typedef __attribute__((ext_vector_type(4))) ushort u16x4;

__device__ inline float b2f(ushort u) {
    unsigned v = ((unsigned)u) << 16;
    float f; __builtin_memcpy(&f, &v, 4); return f;
}
__device__ inline ushort f2b(float f) {   // RNE
    unsigned u; __builtin_memcpy(&u, &f, 4);
    unsigned r = (u + 0x7fffu + ((u >> 16) & 1u)) >> 16;
    return (ushort)r;
}

// ---------------- CSR build: bucketed two-phase ----------------
__global__ __launch_bounds__(256)
void zero_bcnt(int* bcnt) {
    int i = blockIdx.x * 256 + threadIdx.x;
    if (i < NBKT) bcnt[i] = 0;
}

__global__ __launch_bounds__(256)
void bin_count(const int* __restrict__ cols, int* bcnt, int nE) {
    __shared__ int h[NBKT];
    int t = threadIdx.x;
    for (int i = t; i < NBKT; i += 256) h[i] = 0;
    __syncthreads();
    for (long e = (long)blockIdx.x * 256 + t; e < nE; e += (long)gridDim.x * 256)
        atomicAdd(&h[cols[e] >> 8], 1);
    __syncthreads();
    for (int i = t; i < NBKT; i += 256)
        if (h[i]) atomicAdd(&bcnt[i], h[i]);
}

__global__ __launch_bounds__(256)
void bucket_scan(const int* __restrict__ bcnt, int* __restrict__ bbase,
                 int* __restrict__ bcur, int* __restrict__ offsets) {
    __shared__ int sd[256];
    int t = threadIdx.x;
    int i0 = 2 * t, i1 = 2 * t + 1;
    int a = (i0 < NBKT) ? bcnt[i0] : 0;
    int b = (i1 < NBKT) ? bcnt[i1] : 0;
    int s = a + b;
    sd[t] = s; __syncthreads();
    #pragma unroll
    for (int off = 1; off < 256; off <<= 1) {
        int v = (t >= off) ? sd[t - off] : 0;
        __syncthreads();
        sd[t] += v;
        __syncthreads();
    }
    int ex = sd[t] - s;
    if (i0 <= NBKT) bbase[i0] = ex;
    if (i0 < NBKT)  bcur[i0] = ex;
    if (i1 <= NBKT) bbase[i1] = ex + a;
    if (i1 < NBKT)  bcur[i1] = ex + a;
    if (t == 0) offsets[N_NODES] = N_EDGES;
}

// tile -> LDS sort by bucket -> batched reservation -> packed contiguous writes
__global__ __launch_bounds__(256)
void bin_scatter(const int* __restrict__ rows, const int* __restrict__ cols,
                 int* bcur, unsigned* __restrict__ bins, int nE)
{
    __shared__ unsigned recs[TILE];
    __shared__ ushort bos[TILE];
    __shared__ int hist[NBKT], excl[NBKT], cursor[NBKT], gbase[NBKT];
    __shared__ int sd[256];
    int t = threadIdx.x;
    long e0 = (long)blockIdx.x * TILE;
    int cnt = (int)min((long)TILE, (long)nE - e0);
    for (int i = t; i < NBKT; i += 256) hist[i] = 0;
    __syncthreads();
    int myrow[TILE / 256], mycol[TILE / 256];
    #pragma unroll
    for (int k = 0; k < TILE / 256; ++k) {
        int i = k * 256 + t;
        if (i < cnt) {
            myrow[k] = rows[e0 + i];
            mycol[k] = cols[e0 + i];
            atomicAdd(&hist[mycol[k] >> 8], 1);
        }
    }
    __syncthreads();
    {
        int i0 = 2 * t, i1 = 2 * t + 1;
        int a = (i0 < NBKT) ? hist[i0] : 0;
        int b = (i1 < NBKT) ? hist[i1] : 0;
        int s = a + b;
        sd[t] = s; __syncthreads();
        #pragma unroll
        for (int off = 1; off < 256; off <<= 1) {
            int v = (t >= off) ? sd[t - off] : 0;
            __syncthreads();
            sd[t] += v;
            __syncthreads();
        }
        int ex = sd[t] - s;
        if (i0 < NBKT) { excl[i0] = ex;     cursor[i0] = ex; }
        if (i1 < NBKT) { excl[i1] = ex + a; cursor[i1] = ex + a; }
    }
    __syncthreads();
    #pragma unroll
    for (int k = 0; k < TILE / 256; ++k) {
        int i = k * 256 + t;
        if (i < cnt) {
            int b = mycol[k] >> 8;
            int s = atomicAdd(&cursor[b], 1);
            recs[s] = ((unsigned)(mycol[k] & 255) << 24) | (unsigned)myrow[k];
            bos[s] = (ushort)b;
        }
    }
    __syncthreads();
    for (int i = t; i < NBKT; i += 256)
        if (hist[i] > 0) gbase[i] = atomicAdd(&bcur[i], hist[i]);
    __syncthreads();
    for (int i = t; i < cnt; i += 256) {
        int b = bos[i];
        bins[gbase[b] + (i - excl[b])] = recs[i];
    }
}

// one block per bucket: degrees -> dinv/offsets; LDS-staged coalesced esrc
__global__ __launch_bounds__(256)
void bucket_fill(const unsigned* __restrict__ bins, const int* __restrict__ bbase,
                 int* __restrict__ offsets, float* __restrict__ dinv,
                 int* __restrict__ esrc)
{
    int b = blockIdx.x, t = threadIdx.x;
    int s0 = bbase[b], s1 = bbase[b + 1];
    int len = s1 - s0;
    __shared__ int cnt[256];
    __shared__ int sd[256];
    __shared__ int cur[256];
    __shared__ int stage[CAP];
    cnt[t] = 0;
    __syncthreads();
    for (int i = t; i < len; i += 256) atomicAdd(&cnt[bins[s0 + i] >> 24], 1);
    __syncthreads();
    int c = cnt[t];
    sd[t] = c; __syncthreads();
    #pragma unroll
    for (int off = 1; off < 256; off <<= 1) {
        int v = (t >= off) ? sd[t - off] : 0;
        __syncthreads();
        sd[t] += v;
        __syncthreads();
    }
    int ex = sd[t] - c;
    cur[t] = ex;
    int node = b * 256 + t;
    if (node < N_NODES) {
        offsets[node] = s0 + ex;
        dinv[node] = rsqrtf(1.0f + (float)c);
    }
    __syncthreads();
    if (len <= CAP) {
        for (int i = t; i < len; i += 256) {
            unsigned r = bins[s0 + i];
            int p = atomicAdd(&cur[r >> 24], 1);
            stage[p] = (int)(r & 0xFFFFFFu);
        }
        __syncthreads();
        for (int i = t; i < len; i += 256) esrc[s0 + i] = stage[i];
    } else {   // statistically unreachable fallback (correctness guard)
        for (int i = t; i < len; i += 256) {
            unsigned r = bins[s0 + i];
            int p = atomicAdd(&cur[r >> 24], 1);
            esrc[s0 + p] = (int)(r & 0xFFFFFFu);
        }
    }
}

// ---------------- W1 (hi/lo) + W2 -> fragment-ordered bf16, one launch ------
__global__ __launch_bounds__(256)
void fragw(const float* __restrict__ W1, ushort* __restrict__ wfh,
           ushort* __restrict__ wfl,
           const float* __restrict__ W2, ushort* __restrict__ wf2) {
    int t = blockIdx.x * 256 + threadIdx.x;      // 10240 total
    int lane = t & 63;
    int m = lane & 15, quad = lane >> 4;
    if (t < 8192) {                               // W1: 8 ks x 16 nb x 64 lanes
        int ks = t >> 10, nb = (t >> 6) & 15;
        ushort h8[8], l8[8];
        #pragma unroll
        for (int j = 0; j < 8; ++j) {
            int k = ks * 32 + quad * 8 + j;
            float w = W1[k * HIDDEN + nb * 16 + m];
            h8[j] = f2b(w);
            l8[j] = f2b(w - b2f(h8[j]));
        }
        long off = ((long)(ks * 16 + nb) * 64 + lane) * 8;
        *(ushort4*)&wfh[off]     = make_ushort4(h8[0], h8[1], h8[2], h8[3]);
        *(ushort4*)&wfh[off + 4] = make_ushort4(h8[4], h8[5], h8[6], h8[7]);
        *(ushort4*)&wfl[off]     = make_ushort4(l8[0], l8[1], l8[2], l8[3]);
        *(ushort4*)&wfl[off + 4] = make_ushort4(l8[4], l8[5], l8[6], l8[7]);
    } else {                                      // W2: 8 ks x 4 nb x 64 lanes
        int u = t - 8192;
        int ks = u >> 8, nb = (u >> 6) & 3;
        ushort h8[8];
        #pragma unroll
        for (int j = 0; j < 8; ++j) {
            int k = ks * 32 + quad * 8 + j;
            h8[j] = f2b(W2[k * N_CLASSES + nb * 16 + m]);
        }
        long off = ((long)(ks * 4 + nb) * 64 + lane) * 8;
        *(ushort4*)&wf2[off]     = make_ushort4(h8[0], h8[1], h8[2], h8[3]);
        *(ushort4*)&wf2[off + 4] = make_ushort4(h8[4], h8[5], h8[6], h8[7]);
    }
}

// ---------------- x -> fragment-ordered hi/lo bf16 (streaming, BW-bound) ----
__global__ __launch_bounds__(256)
void splitx(const float* __restrict__ x, ushort* __restrict__ xh,
            ushort* __restrict__ xl)
{
    int w = blockIdx.x * 4 + (threadIdx.x >> 6);   // wave id = rb*8 + ks
    int lane = threadIdx.x & 63;
    int rb = w >> 3, ks = w & 7;
    int m = lane & 15, quad = lane >> 4;
    int row = rb * 16 + m;
    float vv[8];
    if (row < N_NODES) {
        const float* p = x + (long)row * D_FEAT + ks * 32 + quad * 8;
        float4 v0 = *(const float4*)p;
        float4 v1 = *(const float4*)(p + 4);
        vv[0] = v0.x; vv[1] = v0.y; vv[2] = v0.z; vv[3] = v0.w;
        vv[4] = v1.x; vv[5] = v1.y; vv[6] = v1.z; vv[7] = v1.w;
    } else {
        #pragma unroll
        for (int j = 0; j < 8; ++j) vv[j] = 0.f;   // pad rows: zero (unstored)
    }
    ushort h8[8], l8[8];
    #pragma unroll
    for (int j = 0; j < 8; ++j) {
        unsigned u; __builtin_memcpy(&u, &vv[j], 4);
        ushort hh = (ushort)(u >> 16);             // truncate hi
        h8[j] = hh;
        l8[j] = f2b(vv[j] - b2f(hh));              // exact remainder, RNE
    }
    long off = ((long)w * 64 + lane) * 8;
    *(ushort4*)&xh[off]     = make_ushort4(h8[0], h8[1], h8[2], h8[3]);
    *(ushort4*)&xh[off + 4] = make_ushort4(h8[4], h8[5], h8[6], h8[7]);
    *(ushort4*)&xl[off]     = make_ushort4(l8[0], l8[1], l8[2], l8[3]);
    *(ushort4*)&xl[off + 4] = make_ushort4(l8[4], l8[5], l8[6], l8[7]);
}

// ---------------- GEMM1: hs = dinv[row] * (x @ W1), 3-product split --------
// Output written CHUNK-MAJOR: hs[chunk=nb][row][16] for L2-resident gather.
__global__ __launch_bounds__(256)
void gemm1_mfma(const ushort* __restrict__ xh, const ushort* __restrict__ xl,
                const ushort* __restrict__ wfh, const ushort* __restrict__ wfl,
                const float* __restrict__ dinv, ushort* __restrict__ hs)
{
    int tid = threadIdx.x;
    int lane = tid & 63;
    int wm = (tid >> 6) & 1;
    int wn = tid >> 7;
    int row0 = blockIdx.y * 128 + wm * 64;
    int rb0 = blockIdx.y * 8 + wm * 4;
    int nb0 = blockIdx.x * 8 + wn * 4;
    int m = lane & 15, quad = lane >> 4;

    f32x4 acc[4][4];
    #pragma unroll
    for (int i = 0; i < 4; ++i)
        #pragma unroll
        for (int j = 0; j < 4; ++j) acc[i][j] = (f32x4){0.f, 0.f, 0.f, 0.f};

    for (int ks = 0; ks < 8; ++ks) {
        bf16x8 ah[4], al[4];
        #pragma unroll
        for (int mf = 0; mf < 4; ++mf) {
            long aoff = (((long)(rb0 + mf) * 8 + ks) * 64 + lane) * 8;
            ah[mf] = *(const bf16x8*)(xh + aoff);
            al[mf] = *(const bf16x8*)(xl + aoff);
        }
        #pragma unroll
        for (int nbl = 0; nbl < 4; ++nbl) {
            long boff = ((long)(ks * 16 + nb0 + nbl) * 64 + lane) * 8;
            bf16x8 bh = *(const bf16x8*)(wfh + boff);
            bf16x8 bl = *(const bf16x8*)(wfl + boff);
            #pragma unroll
            for (int mf = 0; mf < 4; ++mf) {
                acc[mf][nbl] = __builtin_amdgcn_mfma_f32_16x16x32_bf16(ah[mf], bh, acc[mf][nbl], 0, 0, 0);
                acc[mf][nbl] = __builtin_amdgcn_mfma_f32_16x16x32_bf16(ah[mf], bl, acc[mf][nbl], 0, 0, 0);
                acc[mf][nbl] = __builtin_amdgcn_mfma_f32_16x16x32_bf16(al[mf], bh, acc[mf][nbl], 0, 0, 0);
            }
        }
    }

    #pragma unroll
    for (int mf = 0; mf < 4; ++mf)
        #pragma unroll
        for (int reg = 0; reg < 4; ++reg) {
            int row = row0 + mf * 16 + quad * 4 + reg;
            if (row < N_NODES) {
                float dv = dinv[row];
                #pragma unroll
                for (int nbl = 0; nbl < 4; ++nbl)
                    hs[((long)(nb0 + nbl) * NPAD + row) * 16 + m] = f2b(acc[mf][nbl][reg] * dv);
            }
        }
}

// ---------------- GEMM2: h2 = r1s @ W2 (bf16 single) ----------------
// A read from chunk-major r1s [16][NPAD][16]; output chunk-major [4][NPAD][16].
__global__ __launch_bounds__(256)
void gemm2_mfma(const ushort* __restrict__ r1s, const ushort* __restrict__ wf,
                ushort* __restrict__ h2)
{
    int tid = threadIdx.x;
    int wv = tid >> 6, lane = tid & 63;
    int row0 = blockIdx.x * 256 + wv * 64;
    int m = lane & 15, quad = lane >> 4;

    f32x4 acc[4][4];
    #pragma unroll
    for (int i = 0; i < 4; ++i)
        #pragma unroll
        for (int j = 0; j < 4; ++j) acc[i][j] = (f32x4){0.f, 0.f, 0.f, 0.f};

    for (int ks = 0; ks < 8; ++ks) {
        int ca = 2 * ks + (quad >> 1);            // feat chunk of this A frag
        int co = (quad & 1) * 8;                  // offset inside chunk
        bf16x8 a[4];
        #pragma unroll
        for (int mf = 0; mf < 4; ++mf) {
            long r = (long)(row0 + mf * 16 + m);
            a[mf] = *(const bf16x8*)(r1s + ((long)ca * NPAD + r) * 16 + co);
        }
        #pragma unroll
        for (int nb = 0; nb < 4; ++nb) {
            bf16x8 b = *(const bf16x8*)(wf + ((long)(ks * 4 + nb) * 64 + lane) * 8);
            #pragma unroll
            for (int mf = 0; mf < 4; ++mf)
                acc[mf][nb] = __builtin_amdgcn_mfma_f32_16x16x32_bf16(a[mf], b, acc[mf][nb], 0, 0, 0);
        }
    }

    #pragma unroll
    for (int mf = 0; mf < 4; ++mf)
        #pragma unroll
        for (int reg = 0; reg < 4; ++reg) {
            int row = row0 + mf * 16 + quad * 4 + reg;
            if (row < N_NODES) {
                #pragma unroll
                for (int nb = 0; nb < 4; ++nb)
                    h2[((long)nb * NPAD + row) * 16 + m] = f2b(acc[mf][nb][reg]);
            }
        }
}

// ---------------- chunked aggregate: 16-feat chunks, L2-resident gather -----
// grid: (N_NODES/4, NCHUNK); wave = one target x one chunk.
// lane = es*4 + fl: 16 edge slots x 4 feat-lanes (ushort4 = 4 feats each).
__global__ __launch_bounds__(256)
void agg256c(const ushort* __restrict__ src,    // [16][NPAD][16] chunk-major
             const int* __restrict__ offsets, const int* __restrict__ esrc,
             const float* __restrict__ dinv, const float* __restrict__ b1,
             ushort* __restrict__ dst)           // [16][NPAD][16] chunk-major
{
    int wave = threadIdx.x >> 6, lane = threadIdx.x & 63;
    int v = blockIdx.x * 4 + wave;
    int c = blockIdx.y;
    int es = lane >> 2, fl = lane & 3;
    const ushort* cb = src + (long)c * NPAD * 16;
    float a0 = 0.f, a1 = 0.f, a2 = 0.f, a3 = 0.f;
    int e0 = offsets[v], end = offsets[v + 1];
    for (int e = e0 + es; e < end; e += 16) {
        int s = __builtin_nontemporal_load(&esrc[e]);
        ushort4 u = *(const ushort4*)&cb[(long)s * 16 + fl * 4];
        a0 += b2f(u.x); a1 += b2f(u.y); a2 += b2f(u.z); a3 += b2f(u.w);
    }
    #pragma unroll
    for (int msk = 4; msk <= 32; msk <<= 1) {
        a0 += __shfl_xor(a0, msk);
        a1 += __shfl_xor(a1, msk);
        a2 += __shfl_xor(a2, msk);
        a3 += __shfl_xor(a3, msk);
    }
    if (lane < 4) {
        ushort4 s4 = *(const ushort4*)&cb[(long)v * 16 + fl * 4];   // self loop
        a0 += b2f(s4.x); a1 += b2f(s4.y); a2 += b2f(s4.z); a3 += b2f(s4.w);
        float dv = dinv[v];
        float4 bb = *(const float4*)&b1[c * 16 + fl * 4];
        u16x4 o;
        o.x = f2b(dv * fmaxf(fmaf(dv, a0, bb.x), 0.f));
        o.y = f2b(dv * fmaxf(fmaf(dv, a1, bb.y), 0.f));
        o.z = f2b(dv * fmaxf(fmaf(dv, a2, bb.z), 0.f));
        o.w = f2b(dv * fmaxf(fmaf(dv, a3, bb.w), 0.f));
        __builtin_nontemporal_store(o, (u16x4*)&dst[((long)c * NPAD + v) * 16 + fl * 4]);
    }
}

// ---------------- chunked aggregate layer 2: bf16 -> fp32 out ---------------
__global__ __launch_bounds__(256)
void agg64c(const ushort* __restrict__ src,     // [4][NPAD][16] chunk-major
            const int* __restrict__ offsets, const int* __restrict__ esrc,
            const float* __restrict__ dinv, const float* __restrict__ b2,
            float* __restrict__ out)             // [N][64] row-major fp32
{
    int wave = threadIdx.x >> 6, lane = threadIdx.x & 63;
    int v = blockIdx.x * 4 + wave;
    int c = blockIdx.y;
    int es = lane >> 2, fl = lane & 3;
    const ushort* cb = src + (long)c * NPAD * 16;
    float a0 = 0.f, a1 = 0.f, a2 = 0.f, a3 = 0.f;
    int e0 = offsets[v], end = offsets[v + 1];
    for (int e = e0 + es; e < end; e += 16) {
        int s = __builtin_nontemporal_load(&esrc[e]);
        ushort4 u = *(const ushort4*)&cb[(long)s * 16 + fl * 4];
        a0 += b2f(u.x); a1 += b2f(u.y); a2 += b2f(u.z); a3 += b2f(u.w);
    }
    #pragma unroll
    for (int msk = 4; msk <= 32; msk <<= 1) {
        a0 += __shfl_xor(a0, msk);
        a1 += __shfl_xor(a1, msk);
        a2 += __shfl_xor(a2, msk);
        a3 += __shfl_xor(a3, msk);
    }
    if (lane < 4) {
        ushort4 s4 = *(const ushort4*)&cb[(long)v * 16 + fl * 4];   // self loop
        a0 += b2f(s4.x); a1 += b2f(s4.y); a2 += b2f(s4.z); a3 += b2f(s4.w);
        float dv = dinv[v];
        float4 bb = *(const float4*)&b2[c * 16 + fl * 4];
        f32x4 o;
        o.x = fmaf(dv, a0, bb.x);
        o.y = fmaf(dv, a1, bb.y);
        o.z = fmaf(dv, a2, bb.z);
        o.w = fmaf(dv, a3, bb.w);
        __builtin_nontemporal_store(o, (f32x4*)&out[(long)v * 64 + c * 16 + fl * 4]);
    }
}

// ---------------- workspace layout (bytes, 16-aligned) ----------------
// xh/xl dead after gemm1; r1s aliases xh, h2 aliases xl. End 167,647,088 B.
#define WS_DINV   0UL            // 400,000
#define WS_OFFS   400000UL       // 400,004
#define WS_BCNT   800016UL       // 391*4
#define WS_BBASE  801584UL       // 392*4
#define WS_BCUR   803152UL       // 391*4
#define WS_ESRC   804720UL       // 6,400,000
#define WS_BINS   7204720UL      // 6,400,000
#define WS_WF1H   13604720UL     // 131,072
#define WS_WF1L   13735792UL     // 131,072
#define WS_WF2    13866864UL     // 32,768
#define WS_HS1    13899632UL     // 16*NPAD*32 = 51,249,152
#define WS_XH     65148784UL     // 51,249,152
#define WS_XL     116397936UL    // 51,249,152 -> end 167,647,088
#define WS_R1S    WS_XH          // alias: 16*NPAD*32 = 51,249,152 (xh dead)
#define WS_H2     WS_XL          // alias:  4*NPAD*32 = 12,812,288 (xl dead)

extern "C" void kernel_launch(void* const* d_in, const int* in_sizes, int n_in,
                              void* d_out, int out_size, void* d_ws, size_t ws_size,
                              hipStream_t stream)
{
    const float* x  = (const float*)d_in[0];
    const int*   ei = (const int*)d_in[1];
    const float* W1 = (const float*)d_in[2];
    const float* b1 = (const float*)d_in[3];
    const float* W2 = (const float*)d_in[4];
    const float* b2 = (const float*)d_in[5];
    float* out = (float*)d_out;

    const int* rows = ei;            // sources
    const int* cols = ei + N_EDGES;  // targets

    char* ws = (char*)d_ws;
    float*    dinv    = (float*)(ws + WS_DINV);
    int*      offsets = (int*)(ws + WS_OFFS);
    int*      bcnt    = (int*)(ws + WS_BCNT);
    int*      bbase   = (int*)(ws + WS_BBASE);
    int*      bcur    = (int*)(ws + WS_BCUR);
    int*      esrc    = (int*)(ws + WS_ESRC);
    unsigned* bins    = (unsigned*)(ws + WS_BINS);
    ushort*   wf1h    = (ushort*)(ws + WS_WF1H);
    ushort*   wf1l    = (ushort*)(ws + WS_WF1L);
    ushort*   wf2     = (ushort*)(ws + WS_WF2);
    ushort*   hs1     = (ushort*)(ws + WS_HS1);
    ushort*   xh      = (ushort*)(ws + WS_XH);
    ushort*   xl      = (ushort*)(ws + WS_XL);
    ushort*   r1s     = (ushort*)(ws + WS_R1S);
    ushort*   h2      = (ushort*)(ws + WS_H2);

    // --- CSR build (bucketed) ---
    zero_bcnt<<<2, 256, 0, stream>>>(bcnt);
    bin_count<<<512, 256, 0, stream>>>(cols, bcnt, N_EDGES);
    bucket_scan<<<1, 256, 0, stream>>>(bcnt, bbase, bcur, offsets);
    bin_scatter<<<(N_EDGES + TILE - 1) / TILE, 256, 0, stream>>>(rows, cols, bcur, bins, N_EDGES);
    bucket_fill<<<NBKT, 256, 0, stream>>>(bins, bbase, offsets, dinv, esrc);

    // --- weight fragment prep + x hi/lo split (both streaming) ---
    fragw<<<40, 256, 0, stream>>>(W1, wf1h, wf1l, W2, wf2);
    splitx<<<RB_TOT * 8 / 4, 256, 0, stream>>>(x, xh, xl);

    // --- layer 1 ---
    {
        dim3 g1(2, (N_NODES + 127) / 128);
        gemm1_mfma<<<g1, 256, 0, stream>>>(xh, xl, wf1h, wf1l, dinv, hs1);
    }
    {
        dim3 ga(N_NODES / 4, 16);   // x-major dispatch sweeps one chunk at a time
        agg256c<<<ga, 256, 0, stream>>>(hs1, offsets, esrc, dinv, b1, r1s);
    }

    // --- layer 2 ---
    gemm2_mfma<<<(N_NODES + 255) / 256, 256, 0, stream>>>(r1s, wf2, h2);
    {
        dim3 ga(N_NODES / 4, 4);
        agg64c<<<ga, 256, 0, stream>>>(h2, offsets, esrc, dinv, b2, out);
    }
}

// Round 4
// 551.107 us; speedup vs baseline: 1.8350x; 1.8350x over previous
//
#include <hip/hip_runtime.h>
#include <hip/hip_bf16.h>

#define N_NODES 100000
#define N_EDGES 1600000
#define D_FEAT 256
#define HIDDEN 256
#define N_CLASSES 64

#define NBKT 391                // buckets of 256 nodes: 99999>>8 = 390
#define TILE 4096               // edges per bin_scatter block
#define CAP  8192               // bucket_fill LDS staging (mean 4093, sigma 64)
#define RB_TOT 6256             // 16-row blocks covering 782*128 = 100096 rows

typedef __attribute__((ext_vector_type(8))) short bf16x8;
typedef __attribute__((ext_vector_type(4))) float f32x4;
typedef __attribute__((ext_vector_type(4))) ushort u16x4;

__device__ inline float b2f(ushort u) {
    unsigned v = ((unsigned)u) << 16;
    float f; __builtin_memcpy(&f, &v, 4); return f;
}
__device__ inline ushort f2b(float f) {   // RNE
    unsigned u; __builtin_memcpy(&u, &f, 4);
    unsigned r = (u + 0x7fffu + ((u >> 16) & 1u)) >> 16;
    return (ushort)r;
}

// ---------------- CSR build: bucketed two-phase ----------------
__global__ __launch_bounds__(256)
void zero_bcnt(int* bcnt) {
    int i = blockIdx.x * 256 + threadIdx.x;
    if (i < NBKT) bcnt[i] = 0;
}

__global__ __launch_bounds__(256)
void bin_count(const int* __restrict__ cols, int* bcnt, int nE) {
    __shared__ int h[NBKT];
    int t = threadIdx.x;
    for (int i = t; i < NBKT; i += 256) h[i] = 0;
    __syncthreads();
    for (long e = (long)blockIdx.x * 256 + t; e < nE; e += (long)gridDim.x * 256)
        atomicAdd(&h[cols[e] >> 8], 1);
    __syncthreads();
    for (int i = t; i < NBKT; i += 256)
        if (h[i]) atomicAdd(&bcnt[i], h[i]);
}

__global__ __launch_bounds__(256)
void bucket_scan(const int* __restrict__ bcnt, int* __restrict__ bbase,
                 int* __restrict__ bcur, int* __restrict__ offsets) {
    __shared__ int sd[256];
    int t = threadIdx.x;
    int i0 = 2 * t, i1 = 2 * t + 1;
    int a = (i0 < NBKT) ? bcnt[i0] : 0;
    int b = (i1 < NBKT) ? bcnt[i1] : 0;
    int s = a + b;
    sd[t] = s; __syncthreads();
    #pragma unroll
    for (int off = 1; off < 256; off <<= 1) {
        int v = (t >= off) ? sd[t - off] : 0;
        __syncthreads();
        sd[t] += v;
        __syncthreads();
    }
    int ex = sd[t] - s;
    if (i0 <= NBKT) bbase[i0] = ex;
    if (i0 < NBKT)  bcur[i0] = ex;
    if (i1 <= NBKT) bbase[i1] = ex + a;
    if (i1 < NBKT)  bcur[i1] = ex + a;
    if (t == 0) offsets[N_NODES] = N_EDGES;
}

// tile -> LDS sort by bucket -> batched reservation -> packed contiguous writes
__global__ __launch_bounds__(256)
void bin_scatter(const int* __restrict__ rows, const int* __restrict__ cols,
                 int* bcur, unsigned* __restrict__ bins, int nE)
{
    __shared__ unsigned recs[TILE];
    __shared__ ushort bos[TILE];
    __shared__ int hist[NBKT], excl[NBKT], cursor[NBKT], gbase[NBKT];
    __shared__ int sd[256];
    int t = threadIdx.x;
    long e0 = (long)blockIdx.x * TILE;
    int cnt = (int)min((long)TILE, (long)nE - e0);
    for (int i = t; i < NBKT; i += 256) hist[i] = 0;
    __syncthreads();
    int myrow[TILE / 256], mycol[TILE / 256];
    #pragma unroll
    for (int k = 0; k < TILE / 256; ++k) {
        int i = k * 256 + t;
        if (i < cnt) {
            myrow[k] = rows[e0 + i];
            mycol[k] = cols[e0 + i];
            atomicAdd(&hist[mycol[k] >> 8], 1);
        }
    }
    __syncthreads();
    {
        int i0 = 2 * t, i1 = 2 * t + 1;
        int a = (i0 < NBKT) ? hist[i0] : 0;
        int b = (i1 < NBKT) ? hist[i1] : 0;
        int s = a + b;
        sd[t] = s; __syncthreads();
        #pragma unroll
        for (int off = 1; off < 256; off <<= 1) {
            int v = (t >= off) ? sd[t - off] : 0;
            __syncthreads();
            sd[t] += v;
            __syncthreads();
        }
        int ex = sd[t] - s;
        if (i0 < NBKT) { excl[i0] = ex;     cursor[i0] = ex; }
        if (i1 < NBKT) { excl[i1] = ex + a; cursor[i1] = ex + a; }
    }
    __syncthreads();
    #pragma unroll
    for (int k = 0; k < TILE / 256; ++k) {
        int i = k * 256 + t;
        if (i < cnt) {
            int b = mycol[k] >> 8;
            int s = atomicAdd(&cursor[b], 1);
            recs[s] = ((unsigned)(mycol[k] & 255) << 24) | (unsigned)myrow[k];
            bos[s] = (ushort)b;
        }
    }
    __syncthreads();
    for (int i = t; i < NBKT; i += 256)
        if (hist[i] > 0) gbase[i] = atomicAdd(&bcur[i], hist[i]);
    __syncthreads();
    for (int i = t; i < cnt; i += 256) {
        int b = bos[i];
        bins[gbase[b] + (i - excl[b])] = recs[i];
    }
}

// one block per bucket: degrees -> dinv/offsets; LDS-staged coalesced esrc
__global__ __launch_bounds__(256)
void bucket_fill(const unsigned* __restrict__ bins, const int* __restrict__ bbase,
                 int* __restrict__ offsets, float* __restrict__ dinv,
                 int* __restrict__ esrc)
{
    int b = blockIdx.x, t = threadIdx.x;
    int s0 = bbase[b], s1 = bbase[b + 1];
    int len = s1 - s0;
    __shared__ int cnt[256];
    __shared__ int sd[256];
    __shared__ int cur[256];
    __shared__ int stage[CAP];
    cnt[t] = 0;
    __syncthreads();
    for (int i = t; i < len; i += 256) atomicAdd(&cnt[bins[s0 + i] >> 24], 1);
    __syncthreads();
    int c = cnt[t];
    sd[t] = c; __syncthreads();
    #pragma unroll
    for (int off = 1; off < 256; off <<= 1) {
        int v = (t >= off) ? sd[t - off] : 0;
        __syncthreads();
        sd[t] += v;
        __syncthreads();
    }
    int ex = sd[t] - c;
    cur[t] = ex;
    int node = b * 256 + t;
    if (node < N_NODES) {
        offsets[node] = s0 + ex;
        dinv[node] = rsqrtf(1.0f + (float)c);
    }
    __syncthreads();
    if (len <= CAP) {
        for (int i = t; i < len; i += 256) {
            unsigned r = bins[s0 + i];
            int p = atomicAdd(&cur[r >> 24], 1);
            stage[p] = (int)(r & 0xFFFFFFu);
        }
        __syncthreads();
        for (int i = t; i < len; i += 256) esrc[s0 + i] = stage[i];
    } else {   // statistically unreachable fallback (correctness guard)
        for (int i = t; i < len; i += 256) {
            unsigned r = bins[s0 + i];
            int p = atomicAdd(&cur[r >> 24], 1);
            esrc[s0 + p] = (int)(r & 0xFFFFFFu);
        }
    }
}

// ---------------- W1 (hi/lo) + W2 -> fragment-ordered bf16, one launch ------
__global__ __launch_bounds__(256)
void fragw(const float* __restrict__ W1, ushort* __restrict__ wfh,
           ushort* __restrict__ wfl,
           const float* __restrict__ W2, ushort* __restrict__ wf2) {
    int t = blockIdx.x * 256 + threadIdx.x;      // 10240 total
    int lane = t & 63;
    int m = lane & 15, quad = lane >> 4;
    if (t < 8192) {                               // W1: 8 ks x 16 nb x 64 lanes
        int ks = t >> 10, nb = (t >> 6) & 15;
        ushort h8[8], l8[8];
        #pragma unroll
        for (int j = 0; j < 8; ++j) {
            int k = ks * 32 + quad * 8 + j;
            float w = W1[k * HIDDEN + nb * 16 + m];
            h8[j] = f2b(w);
            l8[j] = f2b(w - b2f(h8[j]));
        }
        long off = ((long)(ks * 16 + nb) * 64 + lane) * 8;
        *(ushort4*)&wfh[off]     = make_ushort4(h8[0], h8[1], h8[2], h8[3]);
        *(ushort4*)&wfh[off + 4] = make_ushort4(h8[4], h8[5], h8[6], h8[7]);
        *(ushort4*)&wfl[off]     = make_ushort4(l8[0], l8[1], l8[2], l8[3]);
        *(ushort4*)&wfl[off + 4] = make_ushort4(l8[4], l8[5], l8[6], l8[7]);
    } else {                                      // W2: 8 ks x 4 nb x 64 lanes
        int u = t - 8192;
        int ks = u >> 8, nb = (u >> 6) & 3;
        ushort h8[8];
        #pragma unroll
        for (int j = 0; j < 8; ++j) {
            int k = ks * 32 + quad * 8 + j;
            h8[j] = f2b(W2[k * N_CLASSES + nb * 16 + m]);
        }
        long off = ((long)(ks * 4 + nb) * 64 + lane) * 8;
        *(ushort4*)&wf2[off]     = make_ushort4(h8[0], h8[1], h8[2], h8[3]);
        *(ushort4*)&wf2[off + 4] = make_ushort4(h8[4], h8[5], h8[6], h8[7]);
    }
}

// ---------------- x -> fragment-ordered hi/lo bf16 (streaming, BW-bound) ----
__global__ __launch_bounds__(256)
void splitx(const float* __restrict__ x, ushort* __restrict__ xh,
            ushort* __restrict__ xl)
{
    int w = blockIdx.x * 4 + (threadIdx.x >> 6);   // wave id = rb*8 + ks
    int lane = threadIdx.x & 63;
    int rb = w >> 3, ks = w & 7;
    int m = lane & 15, quad = lane >> 4;
    int row = rb * 16 + m;
    float vv[8];
    if (row < N_NODES) {
        const float* p = x + (long)row * D_FEAT + ks * 32 + quad * 8;
        float4 v0 = *(const float4*)p;
        float4 v1 = *(const float4*)(p + 4);
        vv[0] = v0.x; vv[1] = v0.y; vv[2] = v0.z; vv[3] = v0.w;
        vv[4] = v1.x; vv[5] = v1.y; vv[6] = v1.z; vv[7] = v1.w;
    } else {
        #pragma unroll
        for (int j = 0; j < 8; ++j) vv[j] = 0.f;   // pad rows: zero (unstored)
    }
    ushort h8[8], l8[8];
    #pragma unroll
    for (int j = 0; j < 8; ++j) {
        unsigned u; __builtin_memcpy(&u, &vv[j], 4);
        ushort hh = (ushort)(u >> 16);             // truncate hi
        h8[j] = hh;
        l8[j] = f2b(vv[j] - b2f(hh));              // exact remainder, RNE
    }
    long off = ((long)w * 64 + lane) * 8;
    *(ushort4*)&xh[off]     = make_ushort4(h8[0], h8[1], h8[2], h8[3]);
    *(ushort4*)&xh[off + 4] = make_ushort4(h8[4], h8[5], h8[6], h8[7]);
    *(ushort4*)&xl[off]     = make_ushort4(l8[0], l8[1], l8[2], l8[3]);
    *(ushort4*)&xl[off + 4] = make_ushort4(l8[4], l8[5], l8[6], l8[7]);
}

// ---------------- GEMM1: hs = dinv[row] * (x @ W1), 3-product split --------
// A pre-split + fragment-ordered: pure MFMA loop, all loads 16B coalesced.
__global__ __launch_bounds__(256)
void gemm1_mfma(const ushort* __restrict__ xh, const ushort* __restrict__ xl,
                const ushort* __restrict__ wfh, const ushort* __restrict__ wfl,
                const float* __restrict__ dinv, ushort* __restrict__ hs)
{
    int tid = threadIdx.x;
    int lane = tid & 63;
    int wm = (tid >> 6) & 1;
    int wn = tid >> 7;
    int row0 = blockIdx.y * 128 + wm * 64;
    int rb0 = blockIdx.y * 8 + wm * 4;
    int nb0 = blockIdx.x * 8 + wn * 4;
    int m = lane & 15, quad = lane >> 4;

    f32x4 acc[4][4];
    #pragma unroll
    for (int i = 0; i < 4; ++i)
        #pragma unroll
        for (int j = 0; j < 4; ++j) acc[i][j] = (f32x4){0.f, 0.f, 0.f, 0.f};

    for (int ks = 0; ks < 8; ++ks) {
        bf16x8 ah[4], al[4];
        #pragma unroll
        for (int mf = 0; mf < 4; ++mf) {
            long aoff = (((long)(rb0 + mf) * 8 + ks) * 64 + lane) * 8;
            ah[mf] = *(const bf16x8*)(xh + aoff);
            al[mf] = *(const bf16x8*)(xl + aoff);
        }
        #pragma unroll
        for (int nbl = 0; nbl < 4; ++nbl) {
            long boff = ((long)(ks * 16 + nb0 + nbl) * 64 + lane) * 8;
            bf16x8 bh = *(const bf16x8*)(wfh + boff);
            bf16x8 bl = *(const bf16x8*)(wfl + boff);
            #pragma unroll
            for (int mf = 0; mf < 4; ++mf) {
                acc[mf][nbl] = __builtin_amdgcn_mfma_f32_16x16x32_bf16(ah[mf], bh, acc[mf][nbl], 0, 0, 0);
                acc[mf][nbl] = __builtin_amdgcn_mfma_f32_16x16x32_bf16(ah[mf], bl, acc[mf][nbl], 0, 0, 0);
                acc[mf][nbl] = __builtin_amdgcn_mfma_f32_16x16x32_bf16(al[mf], bh, acc[mf][nbl], 0, 0, 0);
            }
        }
    }

    #pragma unroll
    for (int mf = 0; mf < 4; ++mf)
        #pragma unroll
        for (int reg = 0; reg < 4; ++reg) {
            int row = row0 + mf * 16 + quad * 4 + reg;
            if (row < N_NODES) {
                float dv = dinv[row];
                #pragma unroll
                for (int nbl = 0; nbl < 4; ++nbl)
                    hs[(long)row * HIDDEN + (nb0 + nbl) * 16 + m] = f2b(acc[mf][nbl][reg] * dv);
            }
        }
}

// ---------------- GEMM2: h2 = r1s @ W2 (bf16 single) ----------------
__global__ __launch_bounds__(256)
void gemm2_mfma(const ushort* __restrict__ r1s, const ushort* __restrict__ wf,
                ushort* __restrict__ h2)
{
    int tid = threadIdx.x;
    int wv = tid >> 6, lane = tid & 63;
    int row0 = blockIdx.x * 256 + wv * 64;
    int m = lane & 15, quad = lane >> 4;

    f32x4 acc[4][4];
    #pragma unroll
    for (int i = 0; i < 4; ++i)
        #pragma unroll
        for (int j = 0; j < 4; ++j) acc[i][j] = (f32x4){0.f, 0.f, 0.f, 0.f};

    for (int ks = 0; ks < 8; ++ks) {
        bf16x8 a[4];
        #pragma unroll
        for (int mf = 0; mf < 4; ++mf) {
            long r = (long)(row0 + mf * 16 + m);
            a[mf] = *(const bf16x8*)(r1s + r * HIDDEN + ks * 32 + quad * 8);
        }
        #pragma unroll
        for (int nb = 0; nb < 4; ++nb) {
            bf16x8 b = *(const bf16x8*)(wf + ((long)(ks * 4 + nb) * 64 + lane) * 8);
            #pragma unroll
            for (int mf = 0; mf < 4; ++mf)
                acc[mf][nb] = __builtin_amdgcn_mfma_f32_16x16x32_bf16(a[mf], b, acc[mf][nb], 0, 0, 0);
        }
    }

    #pragma unroll
    for (int mf = 0; mf < 4; ++mf)
        #pragma unroll
        for (int reg = 0; reg < 4; ++reg) {
            int row = row0 + mf * 16 + quad * 4 + reg;
            if (row < N_NODES) {
                #pragma unroll
                for (int nb = 0; nb < 4; ++nb)
                    h2[(long)row * N_CLASSES + nb * 16 + m] = f2b(acc[mf][nb][reg]);
            }
        }
}

// ---------------- aggregate 256 feats bf16, unroll 16/8, NT store ----------
__global__ __launch_bounds__(256)
void agg256(const ushort* __restrict__ src, const int* __restrict__ offsets,
            const int* __restrict__ esrc, const float* __restrict__ dinv,
            const float* __restrict__ b1, ushort* __restrict__ dst)
{
    int wave = threadIdx.x >> 6, lane = threadIdx.x & 63;
    int v = blockIdx.x * 4 + wave;
    int c = lane << 2;
    ushort4 s = *(const ushort4*)&src[(long)v * 256 + c];
    float a0 = b2f(s.x), a1 = b2f(s.y), a2 = b2f(s.z), a3 = b2f(s.w);
    int e = offsets[v], end = offsets[v + 1];
    for (; e + 16 <= end; e += 16) {           // 16 gathers in flight
        ushort4 u[16];
        #pragma unroll
        for (int j = 0; j < 16; ++j)
            u[j] = *(const ushort4*)&src[(long)esrc[e + j] * 256 + c];
        #pragma unroll
        for (int j = 0; j < 16; ++j) {
            a0 += b2f(u[j].x); a1 += b2f(u[j].y);
            a2 += b2f(u[j].z); a3 += b2f(u[j].w);
        }
    }
    for (; e + 8 <= end; e += 8) {
        ushort4 u[8];
        #pragma unroll
        for (int j = 0; j < 8; ++j)
            u[j] = *(const ushort4*)&src[(long)esrc[e + j] * 256 + c];
        #pragma unroll
        for (int j = 0; j < 8; ++j) {
            a0 += b2f(u[j].x); a1 += b2f(u[j].y);
            a2 += b2f(u[j].z); a3 += b2f(u[j].w);
        }
    }
    for (; e < end; ++e) {
        ushort4 u = *(const ushort4*)&src[(long)esrc[e] * 256 + c];
        a0 += b2f(u.x); a1 += b2f(u.y); a2 += b2f(u.z); a3 += b2f(u.w);
    }
    float dv = dinv[v];
    float4 bb = *(const float4*)&b1[c];
    u16x4 o;
    o.x = f2b(dv * fmaxf(fmaf(dv, a0, bb.x), 0.f));
    o.y = f2b(dv * fmaxf(fmaf(dv, a1, bb.y), 0.f));
    o.z = f2b(dv * fmaxf(fmaf(dv, a2, bb.z), 0.f));
    o.w = f2b(dv * fmaxf(fmaf(dv, a3, bb.w), 0.f));
    __builtin_nontemporal_store(o, (u16x4*)&dst[(long)v * 256 + c]);
}

// ---------------- aggregate 64 feats bf16 -> fp32 out, unroll 16/8 ----------
__global__ __launch_bounds__(256)
void agg64b(const ushort* __restrict__ src, const int* __restrict__ offsets,
            const int* __restrict__ esrc, const float* __restrict__ dinv,
            const float* __restrict__ b2, float* __restrict__ out)
{
    int wave = threadIdx.x >> 6, lane = threadIdx.x & 63;
    int v = blockIdx.x * 4 + wave;
    float acc = b2f(src[(long)v * 64 + lane]);
    int e = offsets[v], end = offsets[v + 1];
    for (; e + 16 <= end; e += 16) {
        float a[16];
        #pragma unroll
        for (int j = 0; j < 16; ++j)
            a[j] = b2f(src[(long)esrc[e + j] * 64 + lane]);
        float s0 = ((a[0] + a[1]) + (a[2] + a[3])) + ((a[4] + a[5]) + (a[6] + a[7]));
        float s1 = ((a[8] + a[9]) + (a[10] + a[11])) + ((a[12] + a[13]) + (a[14] + a[15]));
        acc += s0 + s1;
    }
    for (; e + 8 <= end; e += 8) {
        float a[8];
        #pragma unroll
        for (int j = 0; j < 8; ++j)
            a[j] = b2f(src[(long)esrc[e + j] * 64 + lane]);
        acc += ((a[0] + a[1]) + (a[2] + a[3])) + ((a[4] + a[5]) + (a[6] + a[7]));
    }
    for (; e < end; ++e) acc += b2f(src[(long)esrc[e] * 64 + lane]);
    float r = fmaf(dinv[v], acc, b2[lane]);
    __builtin_nontemporal_store(r, &out[(long)v * 64 + lane]);
}

// ---------------- workspace layout (bytes, 16-aligned) ----------------
// xh/xl dead after gemm1; r1s aliases xh, h2 aliases xl. End 167,647,088 B.
#define WS_DINV   0UL            // 400,000
#define WS_OFFS   400000UL       // 400,004
#define WS_BCNT   800016UL       // 391*4
#define WS_BBASE  801584UL       // 392*4
#define WS_BCUR   803152UL       // 391*4
#define WS_ESRC   804720UL       // 6,400,000
#define WS_BINS   7204720UL      // 6,400,000
#define WS_WF1H   13604720UL     // 131,072
#define WS_WF1L   13735792UL     // 131,072
#define WS_WF2    13866864UL     // 32,768
#define WS_HS1    13899632UL     // 51,216,384 (100032*256*2), region 51,249,152
#define WS_XH     65148784UL     // 51,249,152 (RB_TOT*16 = 100096 rows)
#define WS_XL     116397936UL    // 51,249,152 -> end 167,647,088
#define WS_R1S    WS_XH          // alias: 100096*256*2 fits (xh dead)
#define WS_H2     WS_XL          // alias: 100096*64*2 fits (xl dead)

extern "C" void kernel_launch(void* const* d_in, const int* in_sizes, int n_in,
                              void* d_out, int out_size, void* d_ws, size_t ws_size,
                              hipStream_t stream)
{
    const float* x  = (const float*)d_in[0];
    const int*   ei = (const int*)d_in[1];
    const float* W1 = (const float*)d_in[2];
    const float* b1 = (const float*)d_in[3];
    const float* W2 = (const float*)d_in[4];
    const float* b2 = (const float*)d_in[5];
    float* out = (float*)d_out;

    const int* rows = ei;            // sources
    const int* cols = ei + N_EDGES;  // targets

    char* ws = (char*)d_ws;
    float*    dinv    = (float*)(ws + WS_DINV);
    int*      offsets = (int*)(ws + WS_OFFS);
    int*      bcnt    = (int*)(ws + WS_BCNT);
    int*      bbase   = (int*)(ws + WS_BBASE);
    int*      bcur    = (int*)(ws + WS_BCUR);
    int*      esrc    = (int*)(ws + WS_ESRC);
    unsigned* bins    = (unsigned*)(ws + WS_BINS);
    ushort*   wf1h    = (ushort*)(ws + WS_WF1H);
    ushort*   wf1l    = (ushort*)(ws + WS_WF1L);
    ushort*   wf2     = (ushort*)(ws + WS_WF2);
    ushort*   hs1     = (ushort*)(ws + WS_HS1);
    ushort*   xh      = (ushort*)(ws + WS_XH);
    ushort*   xl      = (ushort*)(ws + WS_XL);
    ushort*   r1s     = (ushort*)(ws + WS_R1S);
    ushort*   h2      = (ushort*)(ws + WS_H2);

    // --- CSR build (bucketed) ---
    zero_bcnt<<<2, 256, 0, stream>>>(bcnt);
    bin_count<<<512, 256, 0, stream>>>(cols, bcnt, N_EDGES);
    bucket_scan<<<1, 256, 0, stream>>>(bcnt, bbase, bcur, offsets);
    bin_scatter<<<(N_EDGES + TILE - 1) / TILE, 256, 0, stream>>>(rows, cols, bcur, bins, N_EDGES);
    bucket_fill<<<NBKT, 256, 0, stream>>>(bins, bbase, offsets, dinv, esrc);

    // --- weight fragment prep + x hi/lo split (both streaming) ---
    fragw<<<40, 256, 0, stream>>>(W1, wf1h, wf1l, W2, wf2);
    splitx<<<RB_TOT * 8 / 4, 256, 0, stream>>>(x, xh, xl);

    const int agg_grid = N_NODES / 4;

    // --- layer 1 ---
    {
        dim3 g1(2, (N_NODES + 127) / 128);
        gemm1_mfma<<<g1, 256, 0, stream>>>(xh, xl, wf1h, wf1l, dinv, hs1);
    }
    agg256<<<agg_grid, 256, 0, stream>>>(hs1, offsets, esrc, dinv, b1, r1s);

    // --- layer 2 ---
    gemm2_mfma<<<(N_NODES + 255) / 256, 256, 0, stream>>>(r1s, wf2, h2);
    agg64b<<<agg_grid, 256, 0, stream>>>(h2, offsets, esrc, dinv, b2, out);
}

// Round 5
// 520.818 us; speedup vs baseline: 1.9417x; 1.0582x over previous
//
#include <hip/hip_runtime.h>
#include <hip/hip_bf16.h>

#define N_NODES 100000
#define N_EDGES 1600000
#define D_FEAT 256
#define HIDDEN 256
#define N_CLASSES 64

#define NBKT 391                // buckets of 256 nodes: 99999>>8 = 390
#define TILE 4096               // edges per bin_scatter block
#define CAP  8192               // bucket_fill LDS staging (mean 4093, sigma 64)

typedef __attribute__((ext_vector_type(8))) short bf16x8;
typedef __attribute__((ext_vector_type(4))) float f32x4;

__device__ inline float b2f(ushort u) {
    unsigned v = ((unsigned)u) << 16;
    float f; __builtin_memcpy(&f, &v, 4); return f;
}
__device__ inline ushort f2b(float f) {   // RNE
    unsigned u; __builtin_memcpy(&u, &f, 4);
    unsigned r = (u + 0x7fffu + ((u >> 16) & 1u)) >> 16;
    return (ushort)r;
}

// ---------------- CSR build: bucketed two-phase ----------------
__global__ __launch_bounds__(256)
void zero_bcnt(int* bcnt) {
    int i = blockIdx.x * 256 + threadIdx.x;
    if (i < NBKT) bcnt[i] = 0;
}

__global__ __launch_bounds__(256)
void bin_count(const int* __restrict__ cols, int* bcnt, int nE) {
    __shared__ int h[NBKT];
    int t = threadIdx.x;
    for (int i = t; i < NBKT; i += 256) h[i] = 0;
    __syncthreads();
    for (long e = (long)blockIdx.x * 256 + t; e < nE; e += (long)gridDim.x * 256)
        atomicAdd(&h[cols[e] >> 8], 1);
    __syncthreads();
    for (int i = t; i < NBKT; i += 256)
        if (h[i]) atomicAdd(&bcnt[i], h[i]);
}

__global__ __launch_bounds__(256)
void bucket_scan(const int* __restrict__ bcnt, int* __restrict__ bbase,
                 int* __restrict__ bcur, int* __restrict__ offsets) {
    __shared__ int sd[256];
    int t = threadIdx.x;
    int i0 = 2 * t, i1 = 2 * t + 1;
    int a = (i0 < NBKT) ? bcnt[i0] : 0;
    int b = (i1 < NBKT) ? bcnt[i1] : 0;
    int s = a + b;
    sd[t] = s; __syncthreads();
    #pragma unroll
    for (int off = 1; off < 256; off <<= 1) {
        int v = (t >= off) ? sd[t - off] : 0;
        __syncthreads();
        sd[t] += v;
        __syncthreads();
    }
    int ex = sd[t] - s;
    if (i0 <= NBKT) bbase[i0] = ex;
    if (i0 < NBKT)  bcur[i0] = ex;
    if (i1 <= NBKT) bbase[i1] = ex + a;
    if (i1 < NBKT)  bcur[i1] = ex + a;
    if (t == 0) offsets[N_NODES] = N_EDGES;
}

// tile -> LDS sort by bucket -> batched reservation -> packed contiguous writes
__global__ __launch_bounds__(256)
void bin_scatter(const int* __restrict__ rows, const int* __restrict__ cols,
                 int* bcur, unsigned* __restrict__ bins, int nE)
{
    __shared__ unsigned recs[TILE];
    __shared__ ushort bos[TILE];
    __shared__ int hist[NBKT], excl[NBKT], cursor[NBKT], gbase[NBKT];
    __shared__ int sd[256];
    int t = threadIdx.x;
    long e0 = (long)blockIdx.x * TILE;
    int cnt = (int)min((long)TILE, (long)nE - e0);
    for (int i = t; i < NBKT; i += 256) hist[i] = 0;
    __syncthreads();
    int myrow[TILE / 256], mycol[TILE / 256];
    #pragma unroll
    for (int k = 0; k < TILE / 256; ++k) {
        int i = k * 256 + t;
        if (i < cnt) {
            myrow[k] = rows[e0 + i];
            mycol[k] = cols[e0 + i];
            atomicAdd(&hist[mycol[k] >> 8], 1);
        }
    }
    __syncthreads();
    {
        int i0 = 2 * t, i1 = 2 * t + 1;
        int a = (i0 < NBKT) ? hist[i0] : 0;
        int b = (i1 < NBKT) ? hist[i1] : 0;
        int s = a + b;
        sd[t] = s; __syncthreads();
        #pragma unroll
        for (int off = 1; off < 256; off <<= 1) {
            int v = (t >= off) ? sd[t - off] : 0;
            __syncthreads();
            sd[t] += v;
            __syncthreads();
        }
        int ex = sd[t] - s;
        if (i0 < NBKT) { excl[i0] = ex;     cursor[i0] = ex; }
        if (i1 < NBKT) { excl[i1] = ex + a; cursor[i1] = ex + a; }
    }
    __syncthreads();
    #pragma unroll
    for (int k = 0; k < TILE / 256; ++k) {
        int i = k * 256 + t;
        if (i < cnt) {
            int b = mycol[k] >> 8;
            int s = atomicAdd(&cursor[b], 1);
            recs[s] = ((unsigned)(mycol[k] & 255) << 24) | (unsigned)myrow[k];
            bos[s] = (ushort)b;
        }
    }
    __syncthreads();
    for (int i = t; i < NBKT; i += 256)
        if (hist[i] > 0) gbase[i] = atomicAdd(&bcur[i], hist[i]);
    __syncthreads();
    for (int i = t; i < cnt; i += 256) {
        int b = bos[i];
        bins[gbase[b] + (i - excl[b])] = recs[i];
    }
}

// one block per bucket: degrees -> dinv/offsets; LDS-staged coalesced esrc
__global__ __launch_bounds__(256)
void bucket_fill(const unsigned* __restrict__ bins, const int* __restrict__ bbase,
                 int* __restrict__ offsets, float* __restrict__ dinv,
                 int* __restrict__ esrc)
{
    int b = blockIdx.x, t = threadIdx.x;
    int s0 = bbase[b], s1 = bbase[b + 1];
    int len = s1 - s0;
    __shared__ int cnt[256];
    __shared__ int sd[256];
    __shared__ int cur[256];
    __shared__ int stage[CAP];
    cnt[t] = 0;
    __syncthreads();
    for (int i = t; i < len; i += 256) atomicAdd(&cnt[bins[s0 + i] >> 24], 1);
    __syncthreads();
    int c = cnt[t];
    sd[t] = c; __syncthreads();
    #pragma unroll
    for (int off = 1; off < 256; off <<= 1) {
        int v = (t >= off) ? sd[t - off] : 0;
        __syncthreads();
        sd[t] += v;
        __syncthreads();
    }
    int ex = sd[t] - c;
    cur[t] = ex;
    int node = b * 256 + t;
    if (node < N_NODES) {
        offsets[node] = s0 + ex;
        dinv[node] = rsqrtf(1.0f + (float)c);
    }
    __syncthreads();
    if (len <= CAP) {
        for (int i = t; i < len; i += 256) {
            unsigned r = bins[s0 + i];
            int p = atomicAdd(&cur[r >> 24], 1);
            stage[p] = (int)(r & 0xFFFFFFu);
        }
        __syncthreads();
        for (int i = t; i < len; i += 256) esrc[s0 + i] = stage[i];
    } else {   // statistically unreachable fallback (correctness guard)
        for (int i = t; i < len; i += 256) {
            unsigned r = bins[s0 + i];
            int p = atomicAdd(&cur[r >> 24], 1);
            esrc[s0 + p] = (int)(r & 0xFFFFFFu);
        }
    }
}

// ---------------- W1 (hi/lo) + W2 -> fragment-ordered bf16, one launch ------
__global__ __launch_bounds__(256)
void fragw(const float* __restrict__ W1, ushort* __restrict__ wfh,
           ushort* __restrict__ wfl,
           const float* __restrict__ W2, ushort* __restrict__ wf2) {
    int t = blockIdx.x * 256 + threadIdx.x;      // 10240 total
    int lane = t & 63;
    int m = lane & 15, quad = lane >> 4;
    if (t < 8192) {                               // W1: 8 ks x 16 nb x 64 lanes
        int ks = t >> 10, nb = (t >> 6) & 15;
        ushort h8[8], l8[8];
        #pragma unroll
        for (int j = 0; j < 8; ++j) {
            int k = ks * 32 + quad * 8 + j;
            float w = W1[k * HIDDEN + nb * 16 + m];
            h8[j] = f2b(w);
            l8[j] = f2b(w - b2f(h8[j]));
        }
        long off = ((long)(ks * 16 + nb) * 64 + lane) * 8;
        *(ushort4*)&wfh[off]     = make_ushort4(h8[0], h8[1], h8[2], h8[3]);
        *(ushort4*)&wfh[off + 4] = make_ushort4(h8[4], h8[5], h8[6], h8[7]);
        *(ushort4*)&wfl[off]     = make_ushort4(l8[0], l8[1], l8[2], l8[3]);
        *(ushort4*)&wfl[off + 4] = make_ushort4(l8[4], l8[5], l8[6], l8[7]);
    } else {                                      // W2: 8 ks x 4 nb x 64 lanes
        int u = t - 8192;
        int ks = u >> 8, nb = (u >> 6) & 3;
        ushort h8[8];
        #pragma unroll
        for (int j = 0; j < 8; ++j) {
            int k = ks * 32 + quad * 8 + j;
            h8[j] = f2b(W2[k * N_CLASSES + nb * 16 + m]);
        }
        long off = ((long)(ks * 4 + nb) * 64 + lane) * 8;
        *(ushort4*)&wf2[off]     = make_ushort4(h8[0], h8[1], h8[2], h8[3]);
        *(ushort4*)&wf2[off + 4] = make_ushort4(h8[4], h8[5], h8[6], h8[7]);
    }
}

// ---------------- GEMM1: hs = dinv[row] * (x @ W1), fused split, LDS-staged -
// Per K-step: stage 128x32 fp32 x-tile into LDS with dense coalesced loads
// (XOR-swizzled 16B slots), ds_read_b128 fragments, identical hi/lo split
// (truncate hi, RNE lo) and identical 3-product MFMA order as prior rounds
// -> bit-identical results. Next-tile loads issue under compute (T14-lite).
__global__ __launch_bounds__(256)
void gemm1_mfma(const float* __restrict__ x,
                const ushort* __restrict__ wfh, const ushort* __restrict__ wfl,
                const float* __restrict__ dinv, ushort* __restrict__ hs)
{
    __shared__ f32x4 tile[1024];                 // [128 rows][8 slots] = 16 KB
    int tid = threadIdx.x;
    int lane = tid & 63;
    int wm = (tid >> 6) & 1;
    int wn = tid >> 7;
    int row0 = blockIdx.y * 128 + wm * 64;
    int nb0 = blockIdx.x * 8 + wn * 4;
    int m = lane & 15, quad = lane >> 4;

    // staging geometry: 4 chunks/thread, chunk j -> idx = j*256+tid
    int sr[4], ss[4];                            // local row, swizzled slot
    const float* gp[4];                          // per-thread global base
    #pragma unroll
    for (int j = 0; j < 4; ++j) {
        int idx = j * 256 + tid;
        int lr = idx >> 3, cg = idx & 7;
        sr[j] = lr;
        ss[j] = lr * 8 + (cg ^ (lr & 7));
        int gr = min(blockIdx.y * 128 + lr, N_NODES - 1);   // clamp pad rows
        gp[j] = x + (long)gr * D_FEAT + cg * 4;
    }

    f32x4 acc[4][4];
    #pragma unroll
    for (int i = 0; i < 4; ++i)
        #pragma unroll
        for (int j = 0; j < 4; ++j) acc[i][j] = (f32x4){0.f, 0.f, 0.f, 0.f};

    f32x4 stg[4];
    #pragma unroll
    for (int j = 0; j < 4; ++j) stg[j] = *(const f32x4*)(gp[j]);   // ks=0

    for (int ks = 0; ks < 8; ++ks) {
        #pragma unroll
        for (int j = 0; j < 4; ++j) tile[ss[j]] = stg[j];
        __syncthreads();
        if (ks < 7) {
            #pragma unroll
            for (int j = 0; j < 4; ++j)
                stg[j] = *(const f32x4*)(gp[j] + (ks + 1) * 32);   // prefetch
        }
        bf16x8 ah[4], al[4];
        #pragma unroll
        for (int mf = 0; mf < 4; ++mf) {
            int r = wm * 64 + mf * 16 + m;
            int sw = r & 7;
            f32x4 v0 = tile[r * 8 + ((quad * 2)     ^ sw)];
            f32x4 v1 = tile[r * 8 + ((quad * 2 + 1) ^ sw)];
            float vv[8] = {v0[0], v0[1], v0[2], v0[3], v1[0], v1[1], v1[2], v1[3]};
            #pragma unroll
            for (int j = 0; j < 8; ++j) {
                unsigned u; __builtin_memcpy(&u, &vv[j], 4);
                ushort hh = (ushort)(u >> 16);           // truncate hi
                float hv = b2f(hh);
                ushort ll = f2b(vv[j] - hv);             // exact remainder, RNE
                ah[mf][j] = (short)hh;
                al[mf][j] = (short)ll;
            }
        }
        #pragma unroll
        for (int nbl = 0; nbl < 4; ++nbl) {
            long boff = ((long)(ks * 16 + nb0 + nbl) * 64 + lane) * 8;
            bf16x8 bh = *(const bf16x8*)(wfh + boff);
            bf16x8 bl = *(const bf16x8*)(wfl + boff);
            #pragma unroll
            for (int mf = 0; mf < 4; ++mf) {
                acc[mf][nbl] = __builtin_amdgcn_mfma_f32_16x16x32_bf16(ah[mf], bh, acc[mf][nbl], 0, 0, 0);
                acc[mf][nbl] = __builtin_amdgcn_mfma_f32_16x16x32_bf16(ah[mf], bl, acc[mf][nbl], 0, 0, 0);
                acc[mf][nbl] = __builtin_amdgcn_mfma_f32_16x16x32_bf16(al[mf], bh, acc[mf][nbl], 0, 0, 0);
            }
        }
        __syncthreads();
    }

    #pragma unroll
    for (int mf = 0; mf < 4; ++mf)
        #pragma unroll
        for (int reg = 0; reg < 4; ++reg) {
            int row = row0 + mf * 16 + quad * 4 + reg;
            if (row < N_NODES) {
                float dv = dinv[row];
                #pragma unroll
                for (int nbl = 0; nbl < 4; ++nbl)
                    hs[(long)row * HIDDEN + (nb0 + nbl) * 16 + m] = f2b(acc[mf][nbl][reg] * dv);
            }
        }
}

// ---------------- GEMM2: h2 = r1s @ W2 (bf16 single) ----------------
__global__ __launch_bounds__(256)
void gemm2_mfma(const ushort* __restrict__ r1s, const ushort* __restrict__ wf,
                ushort* __restrict__ h2)
{
    int tid = threadIdx.x;
    int wv = tid >> 6, lane = tid & 63;
    int row0 = blockIdx.x * 256 + wv * 64;
    int m = lane & 15, quad = lane >> 4;

    f32x4 acc[4][4];
    #pragma unroll
    for (int i = 0; i < 4; ++i)
        #pragma unroll
        for (int j = 0; j < 4; ++j) acc[i][j] = (f32x4){0.f, 0.f, 0.f, 0.f};

    for (int ks = 0; ks < 8; ++ks) {
        bf16x8 a[4];
        #pragma unroll
        for (int mf = 0; mf < 4; ++mf) {
            long r = (long)(row0 + mf * 16 + m);
            a[mf] = *(const bf16x8*)(r1s + r * HIDDEN + ks * 32 + quad * 8);
        }
        #pragma unroll
        for (int nb = 0; nb < 4; ++nb) {
            bf16x8 b = *(const bf16x8*)(wf + ((long)(ks * 4 + nb) * 64 + lane) * 8);
            #pragma unroll
            for (int mf = 0; mf < 4; ++mf)
                acc[mf][nb] = __builtin_amdgcn_mfma_f32_16x16x32_bf16(a[mf], b, acc[mf][nb], 0, 0, 0);
        }
    }

    #pragma unroll
    for (int mf = 0; mf < 4; ++mf)
        #pragma unroll
        for (int reg = 0; reg < 4; ++reg) {
            int row = row0 + mf * 16 + quad * 4 + reg;
            if (row < N_NODES) {
                #pragma unroll
                for (int nb = 0; nb < 4; ++nb)
                    h2[(long)row * N_CLASSES + nb * 16 + m] = f2b(acc[mf][nb][reg]);
            }
        }
}

// ---------------- aggregate 256 feats bf16, unroll 8 ----------------
__global__ __launch_bounds__(256)
void agg256(const ushort* __restrict__ src, const int* __restrict__ offsets,
            const int* __restrict__ esrc, const float* __restrict__ dinv,
            const float* __restrict__ b1, ushort* __restrict__ dst)
{
    int wave = threadIdx.x >> 6, lane = threadIdx.x & 63;
    int v = blockIdx.x * 4 + wave;
    int c = lane << 2;
    ushort4 s = *(const ushort4*)&src[(long)v * 256 + c];
    float a0 = b2f(s.x), a1 = b2f(s.y), a2 = b2f(s.z), a3 = b2f(s.w);
    int e = offsets[v], end = offsets[v + 1];
    for (; e + 8 <= end; e += 8) {
        ushort4 u[8];
        #pragma unroll
        for (int j = 0; j < 8; ++j)
            u[j] = *(const ushort4*)&src[(long)esrc[e + j] * 256 + c];
        #pragma unroll
        for (int j = 0; j < 8; ++j) {
            a0 += b2f(u[j].x); a1 += b2f(u[j].y);
            a2 += b2f(u[j].z); a3 += b2f(u[j].w);
        }
    }
    for (; e < end; ++e) {
        ushort4 u = *(const ushort4*)&src[(long)esrc[e] * 256 + c];
        a0 += b2f(u.x); a1 += b2f(u.y); a2 += b2f(u.z); a3 += b2f(u.w);
    }
    float dv = dinv[v];
    float4 bb = *(const float4*)&b1[c];
    float r0 = dv * fmaxf(fmaf(dv, a0, bb.x), 0.f);
    float r1 = dv * fmaxf(fmaf(dv, a1, bb.y), 0.f);
    float r2 = dv * fmaxf(fmaf(dv, a2, bb.z), 0.f);
    float r3 = dv * fmaxf(fmaf(dv, a3, bb.w), 0.f);
    *(ushort4*)&dst[(long)v * 256 + c] = make_ushort4(f2b(r0), f2b(r1), f2b(r2), f2b(r3));
}

// ---------------- aggregate 64 feats bf16 -> fp32 out, unroll 8 -------------
__global__ __launch_bounds__(256)
void agg64b(const ushort* __restrict__ src, const int* __restrict__ offsets,
            const int* __restrict__ esrc, const float* __restrict__ dinv,
            const float* __restrict__ b2, float* __restrict__ out)
{
    int wave = threadIdx.x >> 6, lane = threadIdx.x & 63;
    int v = blockIdx.x * 4 + wave;
    float acc = b2f(src[(long)v * 64 + lane]);
    int e = offsets[v], end = offsets[v + 1];
    for (; e + 8 <= end; e += 8) {
        float a[8];
        #pragma unroll
        for (int j = 0; j < 8; ++j)
            a[j] = b2f(src[(long)esrc[e + j] * 64 + lane]);
        acc += ((a[0] + a[1]) + (a[2] + a[3])) + ((a[4] + a[5]) + (a[6] + a[7]));
    }
    for (; e < end; ++e) acc += b2f(src[(long)esrc[e] * 64 + lane]);
    out[(long)v * 64 + lane] = fmaf(dinv[v], acc, b2[lane]);
}

// ---------------- workspace layout (bytes, 16-aligned) ----------------
#define WS_DINV   0UL            // 400,000
#define WS_OFFS   400000UL       // 400,004
#define WS_BCNT   800016UL       // 391*4
#define WS_BBASE  801584UL       // 392*4
#define WS_BCUR   803152UL       // 391*4
#define WS_ESRC   804720UL       // 6,400,000
#define WS_BINS   7204720UL      // 6,400,000
#define WS_WF1H   13604720UL     // 131,072
#define WS_WF1L   13735792UL     // 131,072
#define WS_WF2    13866864UL     // 32,768
#define WS_HS1    13899632UL     // 51,216,384
#define WS_R1S    65148784UL     // 51,216,384
#define WS_H2     116397936UL    // 12,804,096 -> end ~129.2 MB

extern "C" void kernel_launch(void* const* d_in, const int* in_sizes, int n_in,
                              void* d_out, int out_size, void* d_ws, size_t ws_size,
                              hipStream_t stream)
{
    const float* x  = (const float*)d_in[0];
    const int*   ei = (const int*)d_in[1];
    const float* W1 = (const float*)d_in[2];
    const float* b1 = (const float*)d_in[3];
    const float* W2 = (const float*)d_in[4];
    const float* b2 = (const float*)d_in[5];
    float* out = (float*)d_out;

    const int* rows = ei;            // sources
    const int* cols = ei + N_EDGES;  // targets

    char* ws = (char*)d_ws;
    float*    dinv    = (float*)(ws + WS_DINV);
    int*      offsets = (int*)(ws + WS_OFFS);
    int*      bcnt    = (int*)(ws + WS_BCNT);
    int*      bbase   = (int*)(ws + WS_BBASE);
    int*      bcur    = (int*)(ws + WS_BCUR);
    int*      esrc    = (int*)(ws + WS_ESRC);
    unsigned* bins    = (unsigned*)(ws + WS_BINS);
    ushort*   wf1h    = (ushort*)(ws + WS_WF1H);
    ushort*   wf1l    = (ushort*)(ws + WS_WF1L);
    ushort*   wf2     = (ushort*)(ws + WS_WF2);
    ushort*   hs1     = (ushort*)(ws + WS_HS1);
    ushort*   r1s     = (ushort*)(ws + WS_R1S);
    ushort*   h2      = (ushort*)(ws + WS_H2);

    // --- CSR build (bucketed) ---
    zero_bcnt<<<2, 256, 0, stream>>>(bcnt);
    bin_count<<<512, 256, 0, stream>>>(cols, bcnt, N_EDGES);
    bucket_scan<<<1, 256, 0, stream>>>(bcnt, bbase, bcur, offsets);
    bin_scatter<<<(N_EDGES + TILE - 1) / TILE, 256, 0, stream>>>(rows, cols, bcur, bins, N_EDGES);
    bucket_fill<<<NBKT, 256, 0, stream>>>(bins, bbase, offsets, dinv, esrc);

    // --- weight fragment prep (one launch) ---
    fragw<<<40, 256, 0, stream>>>(W1, wf1h, wf1l, W2, wf2);

    const int agg_grid = N_NODES / 4;

    // --- layer 1 ---
    {
        dim3 g1(2, (N_NODES + 127) / 128);
        gemm1_mfma<<<g1, 256, 0, stream>>>(x, wf1h, wf1l, dinv, hs1);
    }
    agg256<<<agg_grid, 256, 0, stream>>>(hs1, offsets, esrc, dinv, b1, r1s);

    // --- layer 2 ---
    gemm2_mfma<<<(N_NODES + 255) / 256, 256, 0, stream>>>(r1s, wf2, h2);
    agg64b<<<agg_grid, 256, 0, stream>>>(h2, offsets, esrc, dinv, b2, out);
}